// Round 1
// baseline (284.280 us; speedup 1.0000x reference)
//
#include <hip/hip_runtime.h>
#include <cstdint>
#include <cstddef>

#define SEQ 4096
#define DH 2048
#define DOUT 1024

typedef float f32x4 __attribute__((ext_vector_type(4)));
typedef __bf16 bf16x8 __attribute__((ext_vector_type(8)));

// ---- helpers --------------------------------------------------------------

__device__ __forceinline__ unsigned short f2bf(float f) {
  // round-to-nearest-even fp32 -> bf16 (inputs are finite; no NaN handling)
  unsigned int u = __float_as_uint(f);
  unsigned int r = (u + 0x7FFFu + ((u >> 16) & 1u)) >> 16;
  return (unsigned short)r;
}

__device__ __forceinline__ void g2l16(const unsigned short* g, unsigned short* l) {
  // async global -> LDS, 16 bytes per lane. LDS side is wave-uniform base + lane*16.
  __builtin_amdgcn_global_load_lds((__attribute__((address_space(1))) void*)(void*)g,
                                   (__attribute__((address_space(3))) void*)l, 16, 0, 0);
}

// ---- kernel 1: per-row mean / rstd of gate half ---------------------------

__global__ __launch_bounds__(256) void ln_stats(const float* __restrict__ x,
                                                float* __restrict__ mv,
                                                float* __restrict__ rv) {
  int row = blockIdx.x;
  const float4* g4 = (const float4*)(x + (size_t)row * (2 * DH) + DH);
  float4 a = g4[threadIdx.x];
  float4 b = g4[threadIdx.x + 256];
  float s  = a.x + a.y + a.z + a.w + b.x + b.y + b.z + b.w;
  float s2 = a.x * a.x + a.y * a.y + a.z * a.z + a.w * a.w +
             b.x * b.x + b.y * b.y + b.z * b.z + b.w * b.w;
#pragma unroll
  for (int o = 32; o > 0; o >>= 1) {
    s  += __shfl_down(s, o);
    s2 += __shfl_down(s2, o);
  }
  __shared__ float red[8];
  int wave = threadIdx.x >> 6;
  if ((threadIdx.x & 63) == 0) { red[wave] = s; red[wave + 4] = s2; }
  __syncthreads();
  if (threadIdx.x == 0) {
    float S  = red[0] + red[1] + red[2] + red[3];
    float S2 = red[4] + red[5] + red[6] + red[7];
    float mean = S * (1.0f / DH);
    float var  = S2 * (1.0f / DH) - mean * mean;  // ddof=0, matches jnp.var
    mv[row] = mean;
    rv[row] = rsqrtf(var + 1e-5f);
  }
}

// ---- kernel 2: normalize + scale + transpose + cast -> gateT[d][n] bf16 ---

__global__ __launch_bounds__(256) void norm_tr(const float* __restrict__ x,
                                               const float* __restrict__ mv,
                                               const float* __restrict__ rv,
                                               const float* __restrict__ lns,
                                               unsigned short* __restrict__ gateT) {
  __shared__ float tile[64][65];  // +1 pad: conflict-free transposed reads
  int d0 = blockIdx.x * 64;  // d-tile (0..2047)
  int n0 = blockIdx.y * 64;  // n-tile (0..4095)
#pragma unroll
  for (int i = 0; i < 16; i++) {
    int idx = threadIdx.x + i * 256;
    int r = idx >> 6, c = idx & 63;  // r = n offset, c = d offset (coalesced in c)
    float v = x[(size_t)(n0 + r) * (2 * DH) + DH + d0 + c];
    tile[r][c] = (v - mv[n0 + r]) * rv[n0 + r];
  }
  __syncthreads();
#pragma unroll
  for (int i = 0; i < 16; i++) {
    int idx = threadIdx.x + i * 256;
    int dr = idx >> 6, nc = idx & 63;  // coalesced in nc
    float v = tile[nc][dr] * lns[d0 + dr];
    gateT[(size_t)(d0 + dr) * SEQ + n0 + nc] = f2bf(v);
  }
}

// ---- kernel 3: tril-masked cast w fp32 -> bf16 ----------------------------

__global__ __launch_bounds__(256) void cast_w_tril(const float* __restrict__ w,
                                                   unsigned short* __restrict__ wb) {
  size_t e = ((size_t)blockIdx.x * 256 + threadIdx.x) * 8;
  int m = (int)(e >> 12);    // row (4096 = 2^12 cols)
  int k = (int)(e & 4095);   // col
  uint4 o;
  if (k + 7 <= m) {  // fully inside lower triangle
    const float4* s = (const float4*)(w + e);
    float4 a = s[0], b = s[1];
    o.x = (unsigned)f2bf(a.x) | ((unsigned)f2bf(a.y) << 16);
    o.y = (unsigned)f2bf(a.z) | ((unsigned)f2bf(a.w) << 16);
    o.z = (unsigned)f2bf(b.x) | ((unsigned)f2bf(b.y) << 16);
    o.w = (unsigned)f2bf(b.z) | ((unsigned)f2bf(b.w) << 16);
  } else if (k > m) {  // fully above diagonal: no read needed
    o.x = o.y = o.z = o.w = 0u;
  } else {  // straddles the diagonal
    unsigned short t[8];
#pragma unroll
    for (int j = 0; j < 8; j++) t[j] = (k + j <= m) ? f2bf(w[e + j]) : (unsigned short)0;
    o.x = (unsigned)t[0] | ((unsigned)t[1] << 16);
    o.y = (unsigned)t[2] | ((unsigned)t[3] << 16);
    o.z = (unsigned)t[4] | ((unsigned)t[5] << 16);
    o.w = (unsigned)t[6] | ((unsigned)t[7] << 16);
  }
  *(uint4*)(wb + e) = o;
}

// ---- kernel 4: transpose + cast proj_w -> projT[j][d] bf16 ----------------

__global__ __launch_bounds__(256) void proj_tr(const float* __restrict__ pw,
                                               unsigned short* __restrict__ pT) {
  __shared__ float tile[64][65];
  int j0 = blockIdx.x * 64;  // out-col tile (0..1023)
  int d0 = blockIdx.y * 64;  // d tile (0..2047)
#pragma unroll
  for (int i = 0; i < 16; i++) {
    int idx = threadIdx.x + i * 256;
    int r = idx >> 6, c = idx & 63;  // r = d offset, c = j offset
    tile[r][c] = pw[(size_t)(d0 + r) * DOUT + j0 + c];
  }
  __syncthreads();
#pragma unroll
  for (int i = 0; i < 16; i++) {
    int idx = threadIdx.x + i * 256;
    int jr = idx >> 6, dc = idx & 63;
    pT[(size_t)(j0 + jr) * DH + d0 + dc] = f2bf(tile[dc][jr]);
  }
}

// ---- MFMA GEMM, 128xBN tile, BK=64 (m97 structure): C = A(MxK) * BT(NxK)^T
// bf16 in / fp32 acc. 256 threads = 4 waves in a 2x2 grid; each wave owns a
// 64 x (BN/2) subtile = 4 x (BN/32) 16x16 acc frags -> 32 (BN=128) or 16
// (BN=64) MFMA per wave per BK=64 step between barrier pairs (vs 8 at the old
// 64x64 tile — MFMA density is the lever; counters showed latency-bound).
//
// CAUSAL (GEMM1): kEnd = bm0+BM (A pre-masked to tril so the diagonal block
//   is correct). y-remap by = y<16 ? y : 47-y makes the first-dispatched half
//   of the grid the SHORT diagonals and the second half the LONG ones, so
//   under FIFO block dispatch each CU's two blocks sum to ~66 iters (balanced).
// EPI==1: P[m][n] = bf16( xfull[m][n] * (acc + rbias[m]) )
// EPI==2: out[m][n] = acc + cbias[n]
//
// LDS: 128 B rows (BK=64 bf16) = exactly 32 banks, so bank-group of a 16 B
// chunk = its chunk index. XOR-8 swizzle: data chunk c of row R stored at
// physical chunk c^(R&7); frag reads hit all 8 bank-groups with 2 lanes per
// 16-lane phase = conflict-free (0 SQ_LDS_BANK_CONFLICT measured).

template <int BN, int EPI, bool CAUSAL>
__global__ __launch_bounds__(256) void gemm128(const unsigned short* __restrict__ A,
                                               const unsigned short* __restrict__ BT,
                                               const float* __restrict__ xfull,
                                               const float* __restrict__ rbias,
                                               unsigned short* __restrict__ Pout,
                                               const float* __restrict__ cbias,
                                               float* __restrict__ out,
                                               int N, int K) {
  constexpr int BM = 128, BK = 64;
  constexpr int NJ = BN / 32;                    // 16-wide acc frags per wave col
  constexpr int ARPT = (BM * BK) / (256 * 8);    // A 16B-chunks per thread = 4
  constexpr int BRPT = (BN * BK) / (256 * 8);    // B 16B-chunks per thread

  __shared__ unsigned short sA[BM * BK];
  __shared__ unsigned short sB[BN * BK];

  const int tid = threadIdx.x;
  const int lane = tid & 63, wave = tid >> 6;
  const int quad = lane >> 4, l16 = lane & 15;
  const int wm = wave >> 1, wn = wave & 1;
  const int bn0 = blockIdx.x * BN;

  int by = blockIdx.y;
  if (CAUSAL) {
    int half = (int)(gridDim.y >> 1);
    by = (by < half) ? by : ((int)gridDim.y + half - 1) - by;
  }
  const int bm0 = by * BM;
  const int kEnd = CAUSAL ? (bm0 + BM) : K;

  // staging source offsets (row/chunk swizzled), advance by BK per K-step
  const unsigned short* aSrc[ARPT];
  unsigned short* aDst[ARPT];
  const unsigned short* bSrc[BRPT];
  unsigned short* bDst[BRPT];
#pragma unroll
  for (int r = 0; r < ARPT; r++) {
    int idx = r * 256 + tid;
    int row = idx >> 3;
    int col = ((idx & 7) ^ (row & 7)) * 8;
    aSrc[r] = A + (size_t)(bm0 + row) * K + col;
    aDst[r] = &sA[(size_t)idx * 8];
  }
#pragma unroll
  for (int r = 0; r < BRPT; r++) {
    int idx = r * 256 + tid;
    int row = idx >> 3;
    int col = ((idx & 7) ^ (row & 7)) * 8;
    bSrc[r] = BT + (size_t)(bn0 + row) * K + col;
    bDst[r] = &sB[(size_t)idx * 8];
  }

  f32x4 acc[4][NJ] = {};

  for (int k0 = 0; k0 < kEnd; k0 += BK) {
#pragma unroll
    for (int r = 0; r < ARPT; r++) { g2l16(aSrc[r], aDst[r]); aSrc[r] += BK; }
#pragma unroll
    for (int r = 0; r < BRPT; r++) { g2l16(bSrc[r], bDst[r]); bSrc[r] += BK; }
    __syncthreads();  // drains vmcnt (global_load_lds) + barrier

    bf16x8 af[2][4], bfr[2][NJ];
#pragma unroll
    for (int h = 0; h < 2; h++) {
#pragma unroll
      for (int i = 0; i < 4; i++) {
        int R = wm * 64 + i * 16 + l16;
        af[h][i] = *(const bf16x8*)&sA[R * BK + (((h * 4 + quad) ^ (R & 7)) * 8)];
      }
#pragma unroll
      for (int j = 0; j < NJ; j++) {
        int R = wn * (BN / 2) + j * 16 + l16;
        bfr[h][j] = *(const bf16x8*)&sB[R * BK + (((h * 4 + quad) ^ (R & 7)) * 8)];
      }
    }
#pragma unroll
    for (int h = 0; h < 2; h++)
#pragma unroll
      for (int i = 0; i < 4; i++)
#pragma unroll
        for (int j = 0; j < NJ; j++)
          acc[i][j] = __builtin_amdgcn_mfma_f32_16x16x32_bf16(af[h][i], bfr[h][j], acc[i][j], 0, 0, 0);
    __syncthreads();
  }

  // epilogue — C/D layout: col = lane&15, row = quad*4 + reg (m89-verified)
#pragma unroll
  for (int i = 0; i < 4; i++) {
#pragma unroll
    for (int j = 0; j < NJ; j++) {
      int col = bn0 + wn * (BN / 2) + j * 16 + l16;
#pragma unroll
      for (int r = 0; r < 4; r++) {
        int row = bm0 + wm * 64 + i * 16 + quad * 4 + r;
        float v = acc[i][j][r];
        if (EPI == 1) {
          float g = v + rbias[row];
          float pv = xfull[(size_t)row * (2 * DH) + col] * g;
          Pout[(size_t)row * N + col] = f2bf(pv);
        } else {
          out[(size_t)row * N + col] = v + cbias[col];
        }
      }
    }
  }
}

// ---- launch ---------------------------------------------------------------

extern "C" void kernel_launch(void* const* d_in, const int* in_sizes, int n_in,
                              void* d_out, int out_size, void* d_ws, size_t ws_size,
                              hipStream_t stream) {
  (void)in_sizes; (void)n_in; (void)out_size; (void)ws_size;
  const float* x   = (const float*)d_in[0];
  const float* lns = (const float*)d_in[1];
  const float* w   = (const float*)d_in[2];
  const float* sb  = (const float*)d_in[3];
  const float* pw  = (const float*)d_in[4];
  const float* pb  = (const float*)d_in[5];
  float* out = (float*)d_out;

  char* p = (char*)d_ws;
  unsigned short* gateT = (unsigned short*)p; p += (size_t)DH * SEQ * 2;    // 16 MB
  unsigned short* wb    = (unsigned short*)p; p += (size_t)SEQ * SEQ * 2;   // 32 MB
  unsigned short* projT = (unsigned short*)p; p += (size_t)DOUT * DH * 2;   //  4 MB
  unsigned short* Pbuf  = (unsigned short*)p; p += (size_t)SEQ * DH * 2;    // 16 MB
  float* mv = (float*)p; p += (size_t)SEQ * 4;
  float* rv = (float*)p; p += (size_t)SEQ * 4;

  ln_stats<<<SEQ, 256, 0, stream>>>(x, mv, rv);
  norm_tr<<<dim3(DH / 64, SEQ / 64), 256, 0, stream>>>(x, mv, rv, lns, gateT);
  cast_w_tril<<<(int)(((size_t)SEQ * SEQ / 8) / 256), 256, 0, stream>>>(w, wb);
  proj_tr<<<dim3(DOUT / 64, DH / 64), 256, 0, stream>>>(pw, projT);

  // GEMM1: gate2 = tril(w) @ gate  (M=4096, N=2048, K=4096, causal)
  // 128x128 tiles, grid (16,32)=512 blocks (2/CU), self-balancing y remap.
  gemm128<128, 1, true><<<dim3(DH / 128, SEQ / 128), 256, 0, stream>>>(
      wb, gateT, x, sb, Pbuf, nullptr, nullptr, DH, SEQ);
  // GEMM2: out = P @ proj_w + proj_b  (M=4096, N=1024, K=2048)
  // 128x64 tiles, grid (16,32)=512 blocks, 32 uniform iters.
  gemm128<64, 2, false><<<dim3(DOUT / 64, SEQ / 128), 256, 0, stream>>>(
      Pbuf, projT, nullptr, nullptr, nullptr, pb, out, DOUT, DH);
}

// Round 2
// 267.146 us; speedup vs baseline: 1.0641x; 1.0641x over previous
//
#include <hip/hip_runtime.h>
#include <cstdint>
#include <cstddef>

#define SEQ 4096
#define DH 2048
#define DOUT 1024

typedef float f32x4 __attribute__((ext_vector_type(4)));
typedef __bf16 bf16x8 __attribute__((ext_vector_type(8)));

// ---- helpers --------------------------------------------------------------

__device__ __forceinline__ unsigned short f2bf(float f) {
  // round-to-nearest-even fp32 -> bf16 (inputs are finite; no NaN handling)
  unsigned int u = __float_as_uint(f);
  unsigned int r = (u + 0x7FFFu + ((u >> 16) & 1u)) >> 16;
  return (unsigned short)r;
}

__device__ __forceinline__ void g2l16(const unsigned short* g, unsigned short* l) {
  // async global -> LDS, 16 bytes per lane. LDS side is wave-uniform base + lane*16.
  __builtin_amdgcn_global_load_lds((__attribute__((address_space(1))) void*)(void*)g,
                                   (__attribute__((address_space(3))) void*)l, 16, 0, 0);
}

// ---- kernel 1: per-row mean / rstd of gate half ---------------------------

__global__ __launch_bounds__(256) void ln_stats(const float* __restrict__ x,
                                                float* __restrict__ mv,
                                                float* __restrict__ rv) {
  int row = blockIdx.x;
  const float4* g4 = (const float4*)(x + (size_t)row * (2 * DH) + DH);
  float4 a = g4[threadIdx.x];
  float4 b = g4[threadIdx.x + 256];
  float s  = a.x + a.y + a.z + a.w + b.x + b.y + b.z + b.w;
  float s2 = a.x * a.x + a.y * a.y + a.z * a.z + a.w * a.w +
             b.x * b.x + b.y * b.y + b.z * b.z + b.w * b.w;
#pragma unroll
  for (int o = 32; o > 0; o >>= 1) {
    s  += __shfl_down(s, o);
    s2 += __shfl_down(s2, o);
  }
  __shared__ float red[8];
  int wave = threadIdx.x >> 6;
  if ((threadIdx.x & 63) == 0) { red[wave] = s; red[wave + 4] = s2; }
  __syncthreads();
  if (threadIdx.x == 0) {
    float S  = red[0] + red[1] + red[2] + red[3];
    float S2 = red[4] + red[5] + red[6] + red[7];
    float mean = S * (1.0f / DH);
    float var  = S2 * (1.0f / DH) - mean * mean;  // ddof=0, matches jnp.var
    mv[row] = mean;
    rv[row] = rsqrtf(var + 1e-5f);
  }
}

// ---- kernel 2: normalize + scale + transpose + cast -> gateT[d][n] bf16 ---

__global__ __launch_bounds__(256) void norm_tr(const float* __restrict__ x,
                                               const float* __restrict__ mv,
                                               const float* __restrict__ rv,
                                               const float* __restrict__ lns,
                                               unsigned short* __restrict__ gateT) {
  __shared__ float tile[64][65];  // +1 pad: conflict-free transposed reads
  int d0 = blockIdx.x * 64;  // d-tile (0..2047)
  int n0 = blockIdx.y * 64;  // n-tile (0..4095)
#pragma unroll
  for (int i = 0; i < 16; i++) {
    int idx = threadIdx.x + i * 256;
    int r = idx >> 6, c = idx & 63;  // r = n offset, c = d offset (coalesced in c)
    float v = x[(size_t)(n0 + r) * (2 * DH) + DH + d0 + c];
    tile[r][c] = (v - mv[n0 + r]) * rv[n0 + r];
  }
  __syncthreads();
#pragma unroll
  for (int i = 0; i < 16; i++) {
    int idx = threadIdx.x + i * 256;
    int dr = idx >> 6, nc = idx & 63;  // coalesced in nc
    float v = tile[nc][dr] * lns[d0 + dr];
    gateT[(size_t)(d0 + dr) * SEQ + n0 + nc] = f2bf(v);
  }
}

// ---- kernel 3: tril-masked cast w fp32 -> bf16 ----------------------------

__global__ __launch_bounds__(256) void cast_w_tril(const float* __restrict__ w,
                                                   unsigned short* __restrict__ wb) {
  size_t e = ((size_t)blockIdx.x * 256 + threadIdx.x) * 8;
  int m = (int)(e >> 12);    // row (4096 = 2^12 cols)
  int k = (int)(e & 4095);   // col
  uint4 o;
  if (k + 7 <= m) {  // fully inside lower triangle
    const float4* s = (const float4*)(w + e);
    float4 a = s[0], b = s[1];
    o.x = (unsigned)f2bf(a.x) | ((unsigned)f2bf(a.y) << 16);
    o.y = (unsigned)f2bf(a.z) | ((unsigned)f2bf(a.w) << 16);
    o.z = (unsigned)f2bf(b.x) | ((unsigned)f2bf(b.y) << 16);
    o.w = (unsigned)f2bf(b.z) | ((unsigned)f2bf(b.w) << 16);
  } else if (k > m) {  // fully above diagonal: no read needed
    o.x = o.y = o.z = o.w = 0u;
  } else {  // straddles the diagonal
    unsigned short t[8];
#pragma unroll
    for (int j = 0; j < 8; j++) t[j] = (k + j <= m) ? f2bf(w[e + j]) : (unsigned short)0;
    o.x = (unsigned)t[0] | ((unsigned)t[1] << 16);
    o.y = (unsigned)t[2] | ((unsigned)t[3] << 16);
    o.z = (unsigned)t[4] | ((unsigned)t[5] << 16);
    o.w = (unsigned)t[6] | ((unsigned)t[7] << 16);
  }
  *(uint4*)(wb + e) = o;
}

// ---- kernel 4: transpose + cast proj_w -> projT[j][d] bf16 ----------------

__global__ __launch_bounds__(256) void proj_tr(const float* __restrict__ pw,
                                               unsigned short* __restrict__ pT) {
  __shared__ float tile[64][65];
  int j0 = blockIdx.x * 64;  // out-col tile (0..1023)
  int d0 = blockIdx.y * 64;  // d tile (0..2047)
#pragma unroll
  for (int i = 0; i < 16; i++) {
    int idx = threadIdx.x + i * 256;
    int r = idx >> 6, c = idx & 63;  // r = d offset, c = j offset
    tile[r][c] = pw[(size_t)(d0 + r) * DOUT + j0 + c];
  }
  __syncthreads();
#pragma unroll
  for (int i = 0; i < 16; i++) {
    int idx = threadIdx.x + i * 256;
    int jr = idx >> 6, dc = idx & 63;
    pT[(size_t)(j0 + jr) * DH + d0 + dc] = f2bf(tile[dc][jr]);
  }
}

// ---- MFMA GEMM, BMxBN tile, BK=64: C = A(MxK) * BT(NxK)^T -----------------
// bf16 in / fp32 acc. 256 threads = 4 waves in a 2x2 grid; each wave owns a
// (BM/2)x(BN/2) subtile = (BM/32)x(BN/32) 16x16 acc frags.
//   GEMM1: BM=64, BN=128 -> 16 MFMA/wave per barrier-pair, grid 1024 blocks.
//     (Round-1 lesson: 128x128 gave 32 MFMA/wave but only 512 blocks = 2/CU
//      = 2 waves/SIMD -> barrier drain un-hidden, MfmaUtil FELL 21->16%.
//      Density must come WITHOUT losing block-level overlap: LDS 24KB +
//      ~100 VGPR keeps all 1024 blocks co-resident, 4/CU.)
//   GEMM2: BM=64, BN=64 -> round-0 proven config, untouched.
//
// CAUSAL: kEnd = bm0+BM (A pre-masked to tril so diagonal tiles are exact).
//   Load-balance remap (gridDim.y==64): under round-robin placement, CU c
//   hosts linear blocks {c, c+256, c+512, c+768} -> by cosets {r, r+16,
//   r+32, r+48}. Remap to {r, 31-r, 32+r, 63-r}: per-CU iter sum = 130,
//   constant for every r -> uniform finish despite 1..64 iter spread.
// EPI==1: P[m][n] = bf16( xfull[m][n] * (acc + rbias[m]) )
// EPI==2: out[m][n] = acc + cbias[n]
//
// LDS: 128 B rows (BK=64 bf16) = exactly 32 banks; XOR-8 chunk swizzle
// (data chunk c of row R at physical chunk c^(R&7)) -> conflict-free frag
// reads (0 SQ_LDS_BANK_CONFLICT measured rounds 0-1).

template <int BM, int BN, int EPI, bool CAUSAL>
__global__ __launch_bounds__(256) void gemm_t(const unsigned short* __restrict__ A,
                                              const unsigned short* __restrict__ BT,
                                              const float* __restrict__ xfull,
                                              const float* __restrict__ rbias,
                                              unsigned short* __restrict__ Pout,
                                              const float* __restrict__ cbias,
                                              float* __restrict__ out,
                                              int N, int K) {
  constexpr int BK = 64;
  constexpr int MI = BM / 32;                    // acc frags per wave, rows
  constexpr int NJ = BN / 32;                    // acc frags per wave, cols
  constexpr int ARPT = (BM * BK) / (256 * 8);    // A 16B-chunks per thread
  constexpr int BRPT = (BN * BK) / (256 * 8);    // B 16B-chunks per thread

  __shared__ unsigned short sA[BM * BK];
  __shared__ unsigned short sB[BN * BK];

  const int tid = threadIdx.x;
  const int lane = tid & 63, wave = tid >> 6;
  const int quad = lane >> 4, l16 = lane & 15;
  const int wm = wave >> 1, wn = wave & 1;
  const int bn0 = blockIdx.x * BN;

  int by = blockIdx.y;
  if (CAUSAL) {
    // per-CU work-sum-balancing remap (assumes gridDim.y == 64)
    int q = by >> 4, r = by & 15;
    by = (q == 0) ? r : (q == 1) ? (31 - r) : (q == 2) ? (32 + r) : (63 - r);
  }
  const int bm0 = by * BM;
  const int kEnd = CAUSAL ? (bm0 + BM) : K;

  // staging source offsets (row/chunk swizzled), advance by BK per K-step
  const unsigned short* aSrc[ARPT];
  unsigned short* aDst[ARPT];
  const unsigned short* bSrc[BRPT];
  unsigned short* bDst[BRPT];
#pragma unroll
  for (int r = 0; r < ARPT; r++) {
    int idx = r * 256 + tid;
    int row = idx >> 3;
    int col = ((idx & 7) ^ (row & 7)) * 8;
    aSrc[r] = A + (size_t)(bm0 + row) * K + col;
    aDst[r] = &sA[(size_t)idx * 8];
  }
#pragma unroll
  for (int r = 0; r < BRPT; r++) {
    int idx = r * 256 + tid;
    int row = idx >> 3;
    int col = ((idx & 7) ^ (row & 7)) * 8;
    bSrc[r] = BT + (size_t)(bn0 + row) * K + col;
    bDst[r] = &sB[(size_t)idx * 8];
  }

  f32x4 acc[MI][NJ] = {};

  for (int k0 = 0; k0 < kEnd; k0 += BK) {
#pragma unroll
    for (int r = 0; r < ARPT; r++) { g2l16(aSrc[r], aDst[r]); aSrc[r] += BK; }
#pragma unroll
    for (int r = 0; r < BRPT; r++) { g2l16(bSrc[r], bDst[r]); bSrc[r] += BK; }
    __syncthreads();  // drains vmcnt (global_load_lds) + barrier

    bf16x8 af[2][MI], bfr[2][NJ];
#pragma unroll
    for (int h = 0; h < 2; h++) {
#pragma unroll
      for (int i = 0; i < MI; i++) {
        int R = wm * (BM / 2) + i * 16 + l16;
        af[h][i] = *(const bf16x8*)&sA[R * BK + (((h * 4 + quad) ^ (R & 7)) * 8)];
      }
#pragma unroll
      for (int j = 0; j < NJ; j++) {
        int R = wn * (BN / 2) + j * 16 + l16;
        bfr[h][j] = *(const bf16x8*)&sB[R * BK + (((h * 4 + quad) ^ (R & 7)) * 8)];
      }
    }
#pragma unroll
    for (int h = 0; h < 2; h++)
#pragma unroll
      for (int i = 0; i < MI; i++)
#pragma unroll
        for (int j = 0; j < NJ; j++)
          acc[i][j] = __builtin_amdgcn_mfma_f32_16x16x32_bf16(af[h][i], bfr[h][j], acc[i][j], 0, 0, 0);
    __syncthreads();
  }

  // epilogue — C/D layout: col = lane&15, row = quad*4 + reg (m89-verified)
#pragma unroll
  for (int i = 0; i < MI; i++) {
#pragma unroll
    for (int j = 0; j < NJ; j++) {
      int col = bn0 + wn * (BN / 2) + j * 16 + l16;
#pragma unroll
      for (int r = 0; r < 4; r++) {
        int row = bm0 + wm * (BM / 2) + i * 16 + quad * 4 + r;
        float v = acc[i][j][r];
        if (EPI == 1) {
          float g = v + rbias[row];
          float pv = xfull[(size_t)row * (2 * DH) + col] * g;
          Pout[(size_t)row * N + col] = f2bf(pv);
        } else {
          out[(size_t)row * N + col] = v + cbias[col];
        }
      }
    }
  }
}

// ---- launch ---------------------------------------------------------------

extern "C" void kernel_launch(void* const* d_in, const int* in_sizes, int n_in,
                              void* d_out, int out_size, void* d_ws, size_t ws_size,
                              hipStream_t stream) {
  (void)in_sizes; (void)n_in; (void)out_size; (void)ws_size;
  const float* x   = (const float*)d_in[0];
  const float* lns = (const float*)d_in[1];
  const float* w   = (const float*)d_in[2];
  const float* sb  = (const float*)d_in[3];
  const float* pw  = (const float*)d_in[4];
  const float* pb  = (const float*)d_in[5];
  float* out = (float*)d_out;

  char* p = (char*)d_ws;
  unsigned short* gateT = (unsigned short*)p; p += (size_t)DH * SEQ * 2;    // 16 MB
  unsigned short* wb    = (unsigned short*)p; p += (size_t)SEQ * SEQ * 2;   // 32 MB
  unsigned short* projT = (unsigned short*)p; p += (size_t)DOUT * DH * 2;   //  4 MB
  unsigned short* Pbuf  = (unsigned short*)p; p += (size_t)SEQ * DH * 2;    // 16 MB
  float* mv = (float*)p; p += (size_t)SEQ * 4;
  float* rv = (float*)p; p += (size_t)SEQ * 4;

  ln_stats<<<SEQ, 256, 0, stream>>>(x, mv, rv);
  norm_tr<<<dim3(DH / 64, SEQ / 64), 256, 0, stream>>>(x, mv, rv, lns, gateT);
  cast_w_tril<<<(int)(((size_t)SEQ * SEQ / 8) / 256), 256, 0, stream>>>(w, wb);
  proj_tr<<<dim3(DOUT / 64, DH / 64), 256, 0, stream>>>(pw, projT);

  // GEMM1: gate2 = tril(w) @ gate  (M=4096, N=2048, K=4096, causal)
  // 64x128 tiles, grid (16,64)=1024 blocks (4/CU, all co-resident),
  // per-CU-balanced causal remap, 16 MFMA/wave per barrier-pair.
  gemm_t<64, 128, 1, true><<<dim3(DH / 128, SEQ / 64), 256, 0, stream>>>(
      wb, gateT, x, sb, Pbuf, nullptr, nullptr, DH, SEQ);
  // GEMM2: out = P @ proj_w + proj_b  (M=4096, N=1024, K=2048)
  // 64x64 tiles (round-0 proven), grid (16,64)=1024 blocks, 32 uniform iters.
  gemm_t<64, 64, 2, false><<<dim3(DOUT / 64, SEQ / 64), 256, 0, stream>>>(
      Pbuf, projT, nullptr, nullptr, nullptr, pb, out, DOUT, DH);
}